// Round 1
// baseline (214.094 us; speedup 1.0000x reference)
//
#include <hip/hip_runtime.h>
#include <math.h>

// Problem constants (from reference): b=4, n=2048, dim=1024, e=8, top-2
#define BATCH 4
#define SEQ 2048
#define DIM 1024
#define NEXP 8
#define TOKENS (BATCH * SEQ)          // 8192
#define CAP 320                       // int(2048*1.25/8)
#define C4 (CAP / 4)                  // 80 float4 per (b,n,e) row
#define DISP_ELEMS (TOKENS * NEXP * CAP)       // 20,971,520
#define FILL_F4 (DISP_ELEMS / 4)               // 5,242,880 float4 per tensor

struct alignas(16) Rec { float g0, g1; unsigned meta, pad; };

// ws layout (bytes)
#define WS_GSUM_F 0      // float[32]  sum of raw_gates per (b,e)
#define WS_CNT1_F 32     // float[32]  top-1 counts per (b,e)
#define WS_Z2_F   64     // float      sum z^2
#define WS_REC_B  1024                  // Rec[8192] = 131072 B
#define WS_POS0_B (WS_REC_B + 131072)   // int[8192]
#define WS_POS1_B (WS_POS0_B + 32768)   // int[8192]
#define WS_CNT0_B (WS_POS1_B + 32768)   // int[32]

// ---------------------------------------------------------------------------
// Kernel 1: router GEMM + softmax + top2 + threshold routing + loss accums.
// One wave handles 4 tokens; block = 4 waves = 16 tokens; W_g staged in LDS.
// ---------------------------------------------------------------------------
__global__ __launch_bounds__(256) void gating_kernel(
    const float* __restrict__ x, const float* __restrict__ Wg,
    const float* __restrict__ probs, float* __restrict__ ws_f,
    Rec* __restrict__ recs)
{
    __shared__ float Wlds[NEXP * DIM];          // 32 KB
    __shared__ float gsum_l[NEXP];
    __shared__ float cnt1_l[NEXP];
    __shared__ float z2_l;

    const int tid = threadIdx.x;
    float4* W4 = reinterpret_cast<float4*>(Wlds);
    const float4* Wg4 = reinterpret_cast<const float4*>(Wg);
    #pragma unroll
    for (int j = tid; j < NEXP * DIM / 4; j += 256) W4[j] = Wg4[j];
    if (tid < NEXP) { gsum_l[tid] = 0.f; cnt1_l[tid] = 0.f; }
    if (tid == 0) z2_l = 0.f;
    __syncthreads();

    const int wave = tid >> 6, lane = tid & 63;
    const int token0 = blockIdx.x * 16 + wave * 4;
    const int b = (blockIdx.x * 16) >> 11;      // block fully inside one b

    float acc[4][NEXP];
    #pragma unroll
    for (int t = 0; t < 4; ++t)
        #pragma unroll
        for (int e = 0; e < NEXP; ++e) acc[t][e] = 0.f;

    const float4* x4 = reinterpret_cast<const float4*>(x);
    #pragma unroll
    for (int i = 0; i < 4; ++i) {
        const int j = lane + i * 64;            // float4 index in dim (0..255)
        float4 wv[NEXP];
        #pragma unroll
        for (int e = 0; e < NEXP; ++e) wv[e] = W4[e * 256 + j];
        #pragma unroll
        for (int t = 0; t < 4; ++t) {
            const float4 xv = x4[(size_t)(token0 + t) * 256 + j];
            #pragma unroll
            for (int e = 0; e < NEXP; ++e)
                acc[t][e] += xv.x * wv[e].x + xv.y * wv[e].y +
                             xv.z * wv[e].z + xv.w * wv[e].w;
        }
    }
    // wave-wide butterfly reduce each of the 32 partial dots
    #pragma unroll
    for (int t = 0; t < 4; ++t)
        #pragma unroll
        for (int e = 0; e < NEXP; ++e) {
            float v = acc[t][e];
            #pragma unroll
            for (int o = 32; o > 0; o >>= 1) v += __shfl_xor(v, o, 64);
            acc[t][e] = v;
        }

    // per-token epilogue (all lanes redundant; lane 0 commits)
    #pragma unroll
    for (int t = 0; t < 4; ++t) {
        const int token = token0 + t;
        float l[NEXP];
        #pragma unroll
        for (int e = 0; e < NEXP; ++e) l[e] = acc[t][e];
        float m = l[0];
        #pragma unroll
        for (int e = 1; e < NEXP; ++e) m = fmaxf(m, l[e]);
        float ex[NEXP], s = 0.f;
        #pragma unroll
        for (int e = 0; e < NEXP; ++e) { ex[e] = expf(l[e] - m); s += ex[e]; }
        const float inv = 1.f / s;
        // top-2 on logits (ties -> lowest index, matching jax.lax.top_k)
        int e0 = 0; float b0 = l[0];
        #pragma unroll
        for (int e = 1; e < NEXP; ++e) if (l[e] > b0) { b0 = l[e]; e0 = e; }
        int e1 = -1; float b1 = -1e30f;
        #pragma unroll
        for (int e = 0; e < NEXP; ++e)
            if (e != e0 && l[e] > b1) { b1 = l[e]; e1 = e; }
        const float v0 = ex[e0] * inv, v1 = ex[e1] * inv;
        float denom = v0 + v1; if (denom < 1e-9f) denom = 1e-9f;
        const float g0 = v0 / denom, g1 = v1 / denom;
        const float z = m + logf(s);
        // should_route for k=1: probs[1,b,n] < g1 / 0.2 (k=0 always routes)
        const int route = (probs[TOKENS + token] < g1 / 0.2f) ? 1 : 0;
        if (lane == 0) {
            Rec r; r.g0 = g0; r.g1 = g1;
            r.meta = (unsigned)e0 | ((unsigned)e1 << 8) | ((unsigned)route << 16);
            r.pad = 0;
            recs[token] = r;
            #pragma unroll
            for (int e = 0; e < NEXP; ++e) atomicAdd(&gsum_l[e], ex[e] * inv);
            atomicAdd(&cnt1_l[e0], 1.0f);
            atomicAdd(&z2_l, z * z);
        }
    }
    __syncthreads();
    if (tid < NEXP) {
        atomicAdd(&ws_f[WS_GSUM_F + b * NEXP + tid], gsum_l[tid]);
        atomicAdd(&ws_f[WS_CNT1_F + b * NEXP + tid], cnt1_l[tid]);
    }
    if (tid == 0) atomicAdd(&ws_f[WS_Z2_F], z2_l);
}

// ---------------------------------------------------------------------------
// Kernel 2: per-(b,e) exclusive cumsum over n of routing flags (k0 and k1
// packed into one u32), 256-thread Hillis-Steele scan, 8 tokens/thread.
// ---------------------------------------------------------------------------
__global__ __launch_bounds__(256) void scan_kernel(
    const Rec* __restrict__ recs, int* __restrict__ pos0,
    int* __restrict__ pos1, int* __restrict__ cnt0)
{
    const int blk = blockIdx.x;                 // b*8 + e
    const int b = blk >> 3, e = blk & 7;
    const int tid = threadIdx.x;
    __shared__ unsigned lds[256];

    const int base_tok = b * SEQ + tid * 8;
    unsigned f0bits = 0, f1bits = 0;
    #pragma unroll
    for (int j = 0; j < 8; ++j) {
        const unsigned meta = recs[base_tok + j].meta;
        const int e0 = meta & 255, e1 = (meta >> 8) & 255, rt = (meta >> 16) & 1;
        if (e0 == e) f0bits |= 1u << j;
        if (e1 == e && rt) f1bits |= 1u << j;
    }
    const unsigned s0 = __popc(f0bits), s1 = __popc(f1bits);
    const unsigned v = s0 | (s1 << 16);
    lds[tid] = v;
    __syncthreads();
    for (int off = 1; off < 256; off <<= 1) {
        const unsigned t = (tid >= off) ? lds[tid - off] : 0u;
        __syncthreads();
        lds[tid] += t;
        __syncthreads();
    }
    const unsigned inc = lds[tid];
    const unsigned exc = inc - v;
    int p0 = (int)(exc & 0xffffu);
    int p1 = (int)(exc >> 16);
    #pragma unroll
    for (int j = 0; j < 8; ++j) {
        if (f0bits & (1u << j)) pos0[base_tok + j] = p0++;
        if (f1bits & (1u << j)) pos1[base_tok + j] = p1++;
    }
    if (tid == 255) cnt0[blk] = (int)(inc & 0xffffu);
}

// ---------------------------------------------------------------------------
// Kernel 3: fused zero-fill + scatter for dispatch AND combine, plus the two
// scalar losses. One thread per float4 of the capacity axis (5,242,880).
// Routing records (128 KB) stay L2-resident; writes are the roofline.
// ---------------------------------------------------------------------------
__global__ __launch_bounds__(256) void fill_kernel(
    float* __restrict__ out, const Rec* __restrict__ recs,
    const int* __restrict__ pos0, const int* __restrict__ pos1,
    const int* __restrict__ cnt0, const float* __restrict__ ws_f)
{
    const unsigned fid = blockIdx.x * 256u + threadIdx.x;   // < FILL_F4
    const unsigned c4 = fid % (unsigned)C4;
    const unsigned row = fid / (unsigned)C4;                // (b,n,e) row
    const unsigned e = row & 7u;
    const unsigned token = row >> 3;
    const unsigned b = token >> 11;

    const Rec r = recs[token];
    const unsigned e0 = r.meta & 255u;
    const unsigned e1 = (r.meta >> 8) & 255u;
    const unsigned rt = (r.meta >> 16) & 1u;

    const int cbase = (int)(c4 * 4u);
    int p = -1000;                       // sentinel: no hit in this row
    float g = 0.f;
    if (e0 == e) {                        // k=0: capacity check implied by range
        p = pos0[token]; g = r.g0;
    } else if (e1 == e && rt) {
        int c0 = cnt0[b * NEXP + e]; if (c0 > CAP) c0 = CAP;
        const int pp = pos1[token] + c0;
        if (pp < CAP) { p = pp; g = r.g1; }
    }
    const int s = p - cbase;
    float4 comb, disp;
    comb.x = (s == 0) ? g : 0.f; disp.x = (s == 0) ? 1.f : 0.f;
    comb.y = (s == 1) ? g : 0.f; disp.y = (s == 1) ? 1.f : 0.f;
    comb.z = (s == 2) ? g : 0.f; disp.z = (s == 2) ? 1.f : 0.f;
    comb.w = (s == 3) ? g : 0.f; disp.w = (s == 3) ? 1.f : 0.f;

    float4* o4 = reinterpret_cast<float4*>(out);
    o4[fid] = disp;                       // dispatch tensor
    o4[fid + (unsigned)FILL_F4] = comb;   // combine tensor

    if (fid == 0) {
        float bal = 0.f;
        #pragma unroll
        for (int i = 0; i < 32; ++i)
            bal += ws_f[WS_GSUM_F + i] * ws_f[WS_CNT1_F + i];
        bal *= 64.0f / (2048.0f * 2048.0f * 32.0f);
        const float rz = ws_f[WS_Z2_F] / (float)TOKENS;
        out[(size_t)2 * DISP_ELEMS]     = bal;
        out[(size_t)2 * DISP_ELEMS + 1] = rz;
    }
}

// ---------------------------------------------------------------------------
extern "C" void kernel_launch(void* const* d_in, const int* in_sizes, int n_in,
                              void* d_out, int out_size, void* d_ws, size_t ws_size,
                              hipStream_t stream) {
    const float* x     = (const float*)d_in[0];
    const float* Wg    = (const float*)d_in[1];
    const float* probs = (const float*)d_in[2];
    float* out = (float*)d_out;

    char* ws = (char*)d_ws;
    float* ws_f = (float*)ws;                         // accumulators at offset 0
    Rec*  recs  = (Rec*)(ws + WS_REC_B);
    int*  pos0  = (int*)(ws + WS_POS0_B);
    int*  pos1  = (int*)(ws + WS_POS1_B);
    int*  cnt0  = (int*)(ws + WS_CNT0_B);

    // zero the loss accumulators (ws is poisoned 0xAA before every launch)
    hipMemsetAsync(ws, 0, 512, stream);

    gating_kernel<<<TOKENS / 16, 256, 0, stream>>>(x, Wg, probs, ws_f, recs);
    scan_kernel<<<BATCH * NEXP, 256, 0, stream>>>(recs, pos0, pos1, cnt0);
    fill_kernel<<<FILL_F4 / 256, 256, 0, stream>>>(out, recs, pos0, pos1, cnt0, ws_f);
}